// Round 9
// baseline (703.215 us; speedup 1.0000x reference)
//
#include <hip/hip_runtime.h>
#include <math.h>

#define N_NODES 50000
#define N_EDGES 800000
#define D 128

#define TILE_R 32
#define HIST_BLKS ((N_EDGES + 255) / 256)                 // 3125
#define SCAT_BLKS 8192                                    // grid-stride waves
#define GEMM_BLKS ((N_NODES + TILE_R - 1) / TILE_R)       // 1563

typedef float        vf2 __attribute__((ext_vector_type(2)));
typedef unsigned int vu2 __attribute__((ext_vector_type(2)));

// round-to-nearest-even fp32 -> bf16 bits (high 16)
static __device__ __forceinline__ unsigned f2bf(float f) {
    unsigned u = __float_as_uint(f);
    u += 0x7FFFu + ((u >> 16) & 1u);
    return u >> 16;
}

// ---------------------------------------------------------------------------
// count[col[e]]++  (int histogram of destination nodes)
// ---------------------------------------------------------------------------
__global__ __launch_bounds__(256) void hist_kernel(const int* __restrict__ ei,
                                                   int* __restrict__ count) {
    int e = blockIdx.x * blockDim.x + threadIdx.x;
    if (e < N_EDGES) {
        atomicAdd(&count[ei[N_EDGES + e]], 1);
    }
}

// ---------------------------------------------------------------------------
// scan1: per-block (1024) exclusive scan of count -> offset (local),
// block totals -> bsum, dis = rsqrt(count) fused.
// ---------------------------------------------------------------------------
__global__ __launch_bounds__(1024) void scan1_kernel(const int* __restrict__ count,
                                                     int* __restrict__ offset,
                                                     float* __restrict__ dis,
                                                     int* __restrict__ bsum) {
    __shared__ int wsum[16];
    const int tid = threadIdx.x;
    const int lane = tid & 63;
    const int wid = tid >> 6;
    const int i = blockIdx.x * 1024 + tid;

    int c = (i < N_NODES) ? count[i] : 0;
    int inc = c;
#pragma unroll
    for (int d = 1; d < 64; d <<= 1) {
        int v = __shfl_up(inc, d, 64);
        if (lane >= d) inc += v;
    }
    if (lane == 63) wsum[wid] = inc;
    __syncthreads();
    if (wid == 0) {
        int s = (lane < 16) ? wsum[lane] : 0;
#pragma unroll
        for (int d = 1; d < 16; d <<= 1) {
            int v = __shfl_up(s, d, 64);
            if (lane >= d) s += v;
        }
        if (lane < 16) wsum[lane] = s;
    }
    __syncthreads();
    int wpre = (wid > 0) ? wsum[wid - 1] : 0;
    if (i < N_NODES) {
        offset[i] = wpre + inc - c;
        dis[i] = (c > 0) ? rsqrtf((float)c) : 0.0f;
    }
    if (tid == 0) bsum[blockIdx.x] = wsum[15];
}

__global__ __launch_bounds__(1024) void fixup_kernel(const int* __restrict__ bsum,
                                                     int* __restrict__ offset,
                                                     int* __restrict__ cur) {
    __shared__ int pre_s;
    const int tid = threadIdx.x;
    const int blk = blockIdx.x;
    if ((tid >> 6) == 0) {
        int lane = tid & 63;
        int s = 0;
        for (int j = lane; j < blk; j += 64) s += bsum[j];
#pragma unroll
        for (int d = 32; d > 0; d >>= 1) s += __shfl_xor(s, d, 64);
        if (lane == 0) pre_s = s;
    }
    __syncthreads();
    int i = blk * 1024 + tid;
    if (i < N_NODES) {
        int o = offset[i] + pre_s;
        offset[i] = o;
        cur[i] = o;
    }
}

// ---------------------------------------------------------------------------
// FUSED dispatch: gemm (blocks [0, GEMM_BLKS)) || edge-permute scatter (rest).
//
// gemm: h stored ONLY as packed bf16 hpk. Row r (512B): pair p=0..63:
//   word(p*2+0) = {bf16 hm[2p] | bf16 hm[2p+1]<<16}, word(p*2+1) = same for hs.
//
// scatter (ONE WAVE per edge, grid-stride): streams ea in e-order (full BW,
// coalesced 512B rows), packs to bf16, and writes it PERMUTED into col-sorted
// order (eapk, 256B/edge full-line writes — random on the write side where
// there is no latency stall). meta[p] = { row | bf16(dis[row])<<16 } (4B).
// After this, agg's entire ea/meta traffic is SEQUENTIAL.
// ---------------------------------------------------------------------------
__global__ __launch_bounds__(256) void fused_kernel(
    const float* __restrict__ x,
    const float* __restrict__ Wm, const float* __restrict__ bm,
    const float* __restrict__ Ws, const float* __restrict__ bs,
    unsigned* __restrict__ hpk,
    const int* __restrict__ ei, const float* __restrict__ ea,
    const float* __restrict__ dis,
    int* __restrict__ cur, unsigned* __restrict__ meta,
    unsigned* __restrict__ eapk)
{
    __shared__ float xs[TILE_R][D];
    const int tid = threadIdx.x;

    if (blockIdx.x >= GEMM_BLKS) {
        // ---------------- scatter/permute part: one wave per edge ----------------
        const int lane = tid & 63;
        const int gw = (blockIdx.x - GEMM_BLKS) * 4 + (tid >> 6);
        const int nw = SCAT_BLKS * 4;
        for (int e = gw; e < N_EDGES; e += nw) {
            int row = ei[e];                 // wave-uniform
            int col = ei[N_EDGES + e];       // wave-uniform
            // stream ea row (512B coalesced, e-order) and pack to bf16
            vf2 v = __builtin_nontemporal_load((const vf2*)(ea + (size_t)e * D + 2 * lane));
            unsigned pk = f2bf(v[0]) | (f2bf(v[1]) << 16);
            int p = 0;
            if (lane == 0) p = atomicAdd(&cur[col], 1);
            p = __shfl(p, 0);
            // permuted write: 256B full-line, fire-and-forget
            __builtin_nontemporal_store(pk, eapk + (size_t)p * 64 + lane);
            if (lane == 0)
                meta[p] = (unsigned)row | (f2bf(dis[row]) << 16);
        }
        return;
    }

    // ---------------- gemm part ----------------
    const int r0 = blockIdx.x * TILE_R;

    for (int i = tid; i < TILE_R * D / 4; i += 256) {
        int rr = i / (D / 4);
        int cc = (i % (D / 4)) * 4;
        int r = r0 + rr;
        float4 v = make_float4(0.f, 0.f, 0.f, 0.f);
        if (r < N_NODES) v = *(const float4*)(x + (size_t)r * D + cc);
        *(float4*)(&xs[rr][cc]) = v;
    }
    __syncthreads();

    const int m = tid >> 7;              // 0 = mean, 1 = std
    const int p = (tid >> 1) & 63;       // column pair index
    const int rh = tid & 1;              // row half (16 rows each)
    const int c0 = p * 2;
    const float* __restrict__ W = m ? Ws : Wm;
    const float* __restrict__ b = m ? bs : bm;
    const float b0 = b[c0], b1 = b[c0 + 1];

    float acc0[16], acc1[16];
#pragma unroll
    for (int rr = 0; rr < 16; ++rr) { acc0[rr] = b0; acc1[rr] = b1; }

    const float* __restrict__ Wr0 = W + (size_t)c0 * D;
    const float* __restrict__ Wr1 = W + (size_t)(c0 + 1) * D;

    for (int kc = 0; kc < D; kc += 32) {
        float w0[32], w1[32];
#pragma unroll
        for (int j = 0; j < 32; j += 4) {
            float4 a = *(const float4*)(Wr0 + kc + j);
            float4 bb = *(const float4*)(Wr1 + kc + j);
            w0[j] = a.x; w0[j+1] = a.y; w0[j+2] = a.z; w0[j+3] = a.w;
            w1[j] = bb.x; w1[j+1] = bb.y; w1[j+2] = bb.z; w1[j+3] = bb.w;
        }
#pragma unroll
        for (int rr = 0; rr < 16; ++rr) {
            const float* xr = &xs[rh * 16 + rr][kc];
#pragma unroll
            for (int j = 0; j < 32; j += 4) {
                float4 xv = *(const float4*)(xr + j);   // LDS b128, 2-way bcast
                acc0[rr] = fmaf(xv.x, w0[j],     acc0[rr]);
                acc0[rr] = fmaf(xv.y, w0[j + 1], acc0[rr]);
                acc0[rr] = fmaf(xv.z, w0[j + 2], acc0[rr]);
                acc0[rr] = fmaf(xv.w, w0[j + 3], acc0[rr]);
                acc1[rr] = fmaf(xv.x, w1[j],     acc1[rr]);
                acc1[rr] = fmaf(xv.y, w1[j + 1], acc1[rr]);
                acc1[rr] = fmaf(xv.z, w1[j + 2], acc1[rr]);
                acc1[rr] = fmaf(xv.w, w1[j + 3], acc1[rr]);
            }
        }
    }

#pragma unroll
    for (int rr = 0; rr < 16; ++rr) {
        int r = r0 + rh * 16 + rr;
        if (r < N_NODES) {
            unsigned word = f2bf(acc0[rr]) | (f2bf(acc1[rr]) << 16);
            hpk[(size_t)r * 128 + p * 2 + m] = word;
        }
    }
}

// ---------------------------------------------------------------------------
// CSR aggregation: ONE WAVE per node, lane = column pair.
// All bulk traffic is now SEQUENTIAL: meta (4B/edge) and eapk (256B/edge)
// are read in segment order. Only hpk (25.6 MB, L3-resident) is a random
// gather (512B rows), hidden by the batch-8 pipeline.
// ---------------------------------------------------------------------------
__global__ __launch_bounds__(256) void agg_kernel(
    const unsigned* __restrict__ eapk, const vu2* __restrict__ hpk,
    const unsigned* __restrict__ meta,
    const int* __restrict__ offset, const int* __restrict__ cur,
    const float* __restrict__ dis,
    float* __restrict__ om, float* __restrict__ os)
{
    const int tid = threadIdx.x;
    const int lane = tid & 63;
    const int wid = tid >> 6;
    const int n = blockIdx.x * 4 + wid;

    const int start = offset[n];
    const int end = cur[n];          // after scatter, cur[n] == segment end
    const float dc = dis[n];

    // residual row from packed bf16 (issue early; cached buffer)
    vu2 hpn = hpk[(size_t)n * 64 + lane];

    float amx = 0.f, amy = 0.f, asx = 0.f, asy = 0.f;

    for (int jb = start; jb < end; jb += 64) {
        unsigned mt = 0;
        if (jb + lane < end)
            mt = __builtin_nontemporal_load(meta + jb + lane);
        const int mm = min(64, end - jb);

        for (int j0 = 0; j0 < mm; j0 += 8) {
            unsigned eav[8]; vu2 hpv[8]; float drv[8];
#pragma unroll
            for (int u = 0; u < 8; ++u) {
                const int jx = j0 + u;
                const int jj = (jx < mm) ? jx : (mm - 1);   // clamp: valid addr
                unsigned pk = (unsigned)__builtin_amdgcn_readlane((int)mt, jj);
                hpv[u] = hpk[(size_t)(pk & 0xFFFFu) * 64 + lane];      // random, L3
                eav[u] = __builtin_nontemporal_load(
                    eapk + (size_t)(jb + jj) * 64 + lane);             // sequential
                drv[u] = (jx < mm) ? __uint_as_float(pk & 0xFFFF0000u) : 0.0f;
            }
#pragma unroll
            for (int u = 0; u < 8; ++u) {
                float eax = __uint_as_float(eav[u] << 16);
                float eay = __uint_as_float(eav[u] & 0xFFFF0000u);
                float h0 = __uint_as_float(hpv[u][0] << 16);
                float h1 = __uint_as_float(hpv[u][0] & 0xFFFF0000u);
                float g0 = __uint_as_float(hpv[u][1] << 16);
                float g1 = __uint_as_float(hpv[u][1] & 0xFFFF0000u);
                amx = fmaf(drv[u], h0 + eax, amx);
                amy = fmaf(drv[u], h1 + eay, amy);
                asx = fmaf(drv[u], g0 + eax, asx);
                asy = fmaf(drv[u], g1 + eay, asy);
            }
        }
    }

    const size_t ob = (size_t)n * D + 2 * lane;
    vf2 o0, o1;
    o0[0] = __uint_as_float(hpn[0] << 16)         + dc * amx;
    o0[1] = __uint_as_float(hpn[0] & 0xFFFF0000u) + dc * amy;
    o1[0] = __uint_as_float(hpn[1] << 16)         + dc * asx;
    o1[1] = __uint_as_float(hpn[1] & 0xFFFF0000u) + dc * asy;
    __builtin_nontemporal_store(o0, (vf2*)(om + ob));
    __builtin_nontemporal_store(o1, (vf2*)(os + ob));
}

extern "C" void kernel_launch(void* const* d_in, const int* in_sizes, int n_in,
                              void* d_out, int out_size, void* d_ws, size_t ws_size,
                              hipStream_t stream) {
    const float* x   = (const float*)d_in[0];
    const int*   ei  = (const int*)d_in[1];     // [2, E] int32
    const float* ea  = (const float*)d_in[2];   // [E, D]
    const float* Wm  = (const float*)d_in[3];
    const float* bm  = (const float*)d_in[4];
    const float* Ws  = (const float*)d_in[5];
    const float* bs  = (const float*)d_in[6];
    float* out = (float*)d_out;                 // [2, N, D]

    // workspace layout (16B-aligned chunks)
    char* w = (char*)d_ws;
    int*   count  = (int*)w;      w += (size_t)N_NODES * 4;
    int*   offset = (int*)w;      w += (size_t)N_NODES * 4;
    int*   cur    = (int*)w;      w += (size_t)N_NODES * 4;
    float* dis    = (float*)w;    w += (size_t)N_NODES * 4;
    int*   bsum   = (int*)w;      w += 4096;
    unsigned* meta = (unsigned*)w; w += (size_t)N_EDGES * 4;        // 3.2 MB
    unsigned* hpk  = (unsigned*)w; w += (size_t)N_NODES * 128 * 4;  // 25.6 MB
    unsigned* eapk = (unsigned*)w;                                  // 204.8 MB
    float* om = out;
    float* os = out + (size_t)N_NODES * D;

    const int SCAN_BLKS = (N_NODES + 1023) / 1024;   // 49

    // 1. zero histogram (ws poisoned 0xAA once, never re-poisoned)
    hipMemsetAsync(count, 0, N_NODES * sizeof(int), stream);

    // 2. histogram of destinations
    hist_kernel<<<HIST_BLKS, 256, 0, stream>>>(ei, count);

    // 3-4. parallel exclusive scan (+ dis = rsqrt(deg) fused)
    scan1_kernel<<<SCAN_BLKS, 1024, 0, stream>>>(count, offset, dis, bsum);
    fixup_kernel<<<SCAN_BLKS, 1024, 0, stream>>>(bsum, offset, cur);

    // 5. gemm || ea-permute scatter (single fused dispatch)
    fused_kernel<<<GEMM_BLKS + SCAT_BLKS, 256, 0, stream>>>(
        x, Wm, bm, Ws, bs, hpk, ei, ea, dis, cur, meta, eapk);

    // 6. CSR aggregation: sequential eapk/meta streams + L3-resident hpk gather
    agg_kernel<<<N_NODES / 4, 256, 0, stream>>>(
        eapk, (const vu2*)hpk, meta, offset, cur, dis, om, os);
}

// Round 10
// 297.462 us; speedup vs baseline: 2.3640x; 2.3640x over previous
//
#include <hip/hip_runtime.h>
#include <math.h>

#define N_NODES 50000
#define N_EDGES 800000
#define D 128

#define TILE_R 32
#define HIST_BLKS ((N_EDGES + 255) / 256)                 // 3125
#define SCAT_BLKS HIST_BLKS
#define GEMM_BLKS ((N_NODES + TILE_R - 1) / TILE_R)       // 1563

typedef float        vf2 __attribute__((ext_vector_type(2)));
typedef unsigned int vu2 __attribute__((ext_vector_type(2)));

// round-to-nearest-even fp32 -> bf16 bits (high 16)
static __device__ __forceinline__ unsigned f2bf(float f) {
    unsigned u = __float_as_uint(f);
    u += 0x7FFFu + ((u >> 16) & 1u);
    return u >> 16;
}

// ---------------------------------------------------------------------------
// count[col[e]]++  (int histogram of destination nodes)
// ---------------------------------------------------------------------------
__global__ __launch_bounds__(256) void hist_kernel(const int* __restrict__ ei,
                                                   int* __restrict__ count) {
    int e = blockIdx.x * blockDim.x + threadIdx.x;
    if (e < N_EDGES) {
        atomicAdd(&count[ei[N_EDGES + e]], 1);
    }
}

// ---------------------------------------------------------------------------
// scan1: per-block (1024) exclusive scan of count -> offset (local),
// block totals -> bsum, dis = rsqrt(count) fused.
// ---------------------------------------------------------------------------
__global__ __launch_bounds__(1024) void scan1_kernel(const int* __restrict__ count,
                                                     int* __restrict__ offset,
                                                     float* __restrict__ dis,
                                                     int* __restrict__ bsum) {
    __shared__ int wsum[16];
    const int tid = threadIdx.x;
    const int lane = tid & 63;
    const int wid = tid >> 6;
    const int i = blockIdx.x * 1024 + tid;

    int c = (i < N_NODES) ? count[i] : 0;
    int inc = c;
#pragma unroll
    for (int d = 1; d < 64; d <<= 1) {
        int v = __shfl_up(inc, d, 64);
        if (lane >= d) inc += v;
    }
    if (lane == 63) wsum[wid] = inc;
    __syncthreads();
    if (wid == 0) {
        int s = (lane < 16) ? wsum[lane] : 0;
#pragma unroll
        for (int d = 1; d < 16; d <<= 1) {
            int v = __shfl_up(s, d, 64);
            if (lane >= d) s += v;
        }
        if (lane < 16) wsum[lane] = s;
    }
    __syncthreads();
    int wpre = (wid > 0) ? wsum[wid - 1] : 0;
    if (i < N_NODES) {
        offset[i] = wpre + inc - c;
        dis[i] = (c > 0) ? rsqrtf((float)c) : 0.0f;
    }
    if (tid == 0) bsum[blockIdx.x] = wsum[15];
}

__global__ __launch_bounds__(1024) void fixup_kernel(const int* __restrict__ bsum,
                                                     int* __restrict__ offset,
                                                     int* __restrict__ cur) {
    __shared__ int pre_s;
    const int tid = threadIdx.x;
    const int blk = blockIdx.x;
    if ((tid >> 6) == 0) {
        int lane = tid & 63;
        int s = 0;
        for (int j = lane; j < blk; j += 64) s += bsum[j];
#pragma unroll
        for (int d = 32; d > 0; d >>= 1) s += __shfl_xor(s, d, 64);
        if (lane == 0) pre_s = s;
    }
    __syncthreads();
    int i = blk * 1024 + tid;
    if (i < N_NODES) {
        int o = offset[i] + pre_s;
        offset[i] = o;
        cur[i] = o;
    }
}

// ---------------------------------------------------------------------------
// FUSED: counting-sort scatter (blocks [0, SCAT_BLKS)) || gemm (rest).
// Scatter blocks FIRST: they're the latency-bound long pole — front-loading
// them in dispatch order overlaps their latency under the gemm blocks.
//
// scatter: meta[cur[col]++] = { e, row | bf16(dis[row])<<16 }  (8 B/edge,
//          one INDEPENDENT atomic chain per thread — not per wave)
// gemm: h stored ONLY as packed bf16 hpk. Row r (512B): pair p=0..63:
//   word(p*2+0) = {bf16 hm[2p] | bf16 hm[2p+1]<<16}, word(p*2+1) = same for hs.
// ---------------------------------------------------------------------------
__global__ __launch_bounds__(256) void fused_kernel(
    const float* __restrict__ x,
    const float* __restrict__ Wm, const float* __restrict__ bm,
    const float* __restrict__ Ws, const float* __restrict__ bs,
    unsigned* __restrict__ hpk,
    const int* __restrict__ ei, const float* __restrict__ dis,
    int* __restrict__ cur, vu2* __restrict__ meta)
{
    __shared__ float xs[TILE_R][D];
    const int tid = threadIdx.x;

    if (blockIdx.x < SCAT_BLKS) {
        // ---------------- scatter part (thread-per-edge) ----------------
        int e = blockIdx.x * 256 + tid;
        if (e < N_EDGES) {
            int row = ei[e];
            int col = ei[N_EDGES + e];
            int p = atomicAdd(&cur[col], 1);
            vu2 v;
            v[0] = (unsigned)e;
            v[1] = (unsigned)row | (f2bf(dis[row]) << 16);
            meta[p] = v;
        }
        return;
    }

    // ---------------- gemm part ----------------
    const int r0 = (blockIdx.x - SCAT_BLKS) * TILE_R;

    for (int i = tid; i < TILE_R * D / 4; i += 256) {
        int rr = i / (D / 4);
        int cc = (i % (D / 4)) * 4;
        int r = r0 + rr;
        float4 v = make_float4(0.f, 0.f, 0.f, 0.f);
        if (r < N_NODES) v = *(const float4*)(x + (size_t)r * D + cc);
        *(float4*)(&xs[rr][cc]) = v;
    }
    __syncthreads();

    const int m = tid >> 7;              // 0 = mean, 1 = std
    const int p = (tid >> 1) & 63;       // column pair index
    const int rh = tid & 1;              // row half (16 rows each)
    const int c0 = p * 2;
    const float* __restrict__ W = m ? Ws : Wm;
    const float* __restrict__ b = m ? bs : bm;
    const float b0 = b[c0], b1 = b[c0 + 1];

    float acc0[16], acc1[16];
#pragma unroll
    for (int rr = 0; rr < 16; ++rr) { acc0[rr] = b0; acc1[rr] = b1; }

    const float* __restrict__ Wr0 = W + (size_t)c0 * D;
    const float* __restrict__ Wr1 = W + (size_t)(c0 + 1) * D;

    for (int kc = 0; kc < D; kc += 32) {
        float w0[32], w1[32];
#pragma unroll
        for (int j = 0; j < 32; j += 4) {
            float4 a = *(const float4*)(Wr0 + kc + j);
            float4 bb = *(const float4*)(Wr1 + kc + j);
            w0[j] = a.x; w0[j+1] = a.y; w0[j+2] = a.z; w0[j+3] = a.w;
            w1[j] = bb.x; w1[j+1] = bb.y; w1[j+2] = bb.z; w1[j+3] = bb.w;
        }
#pragma unroll
        for (int rr = 0; rr < 16; ++rr) {
            const float* xr = &xs[rh * 16 + rr][kc];
#pragma unroll
            for (int j = 0; j < 32; j += 4) {
                float4 xv = *(const float4*)(xr + j);   // LDS b128, 2-way bcast
                acc0[rr] = fmaf(xv.x, w0[j],     acc0[rr]);
                acc0[rr] = fmaf(xv.y, w0[j + 1], acc0[rr]);
                acc0[rr] = fmaf(xv.z, w0[j + 2], acc0[rr]);
                acc0[rr] = fmaf(xv.w, w0[j + 3], acc0[rr]);
                acc1[rr] = fmaf(xv.x, w1[j],     acc1[rr]);
                acc1[rr] = fmaf(xv.y, w1[j + 1], acc1[rr]);
                acc1[rr] = fmaf(xv.z, w1[j + 2], acc1[rr]);
                acc1[rr] = fmaf(xv.w, w1[j + 3], acc1[rr]);
            }
        }
    }

#pragma unroll
    for (int rr = 0; rr < 16; ++rr) {
        int r = r0 + rh * 16 + rr;
        if (r < N_NODES) {
            unsigned word = f2bf(acc0[rr]) | (f2bf(acc1[rr]) << 16);
            hpk[(size_t)r * 128 + p * 2 + m] = word;
        }
    }
}

// ---------------------------------------------------------------------------
// CSR aggregation: ONE WAVE per node, lane = column pair (8B).
// BATCH-8: per 8 edges, issue all 16 independent loads upfront into
// fully-unrolled register arrays (compile-time indices), then consume.
// No min-waves bound (a forced VGPR cap was the r6/r7 regression).
// Single-touch streams (meta, ea, out) nontemporal; hpk stays cached.
// Model: ~880 MB via vector path (ea 410 HBM-random + hpk 410 L3 + meta
// + out) at ~5 TB/s combined -> ~175 us; near the pattern's ceiling.
// ---------------------------------------------------------------------------
__global__ __launch_bounds__(256) void agg_kernel(
    const float* __restrict__ eap, const vu2* __restrict__ hpk,
    const vu2* __restrict__ meta,
    const int* __restrict__ offset, const int* __restrict__ cur,
    const float* __restrict__ dis,
    float* __restrict__ om, float* __restrict__ os)
{
    const int tid = threadIdx.x;
    const int lane = tid & 63;
    const int wid = tid >> 6;
    const int n = blockIdx.x * 4 + wid;

    const int start = offset[n];
    const int end = cur[n];          // after scatter, cur[n] == segment end
    const float dc = dis[n];
    const int k = lane * 2;

    // residual row from packed bf16 (issue early; cached buffer)
    vu2 hpn = hpk[(size_t)n * 64 + lane];

    float amx = 0.f, amy = 0.f, asx = 0.f, asy = 0.f;

    for (int jb = start; jb < end; jb += 64) {
        vu2 mt = (vu2)(0);
        if (jb + lane < end)
            mt = __builtin_nontemporal_load(meta + jb + lane);
        const int mm = min(64, end - jb);

        for (int j0 = 0; j0 < mm; j0 += 8) {
            vf2 eav[8]; vu2 hpv[8]; float drv[8];
#pragma unroll
            for (int u = 0; u < 8; ++u) {
                const int jx = j0 + u;
                const int jj = (jx < mm) ? jx : (mm - 1);   // clamp: valid addr
                unsigned ev = (unsigned)__builtin_amdgcn_readlane((int)mt[0], jj);
                unsigned pk = (unsigned)__builtin_amdgcn_readlane((int)mt[1], jj);
                eav[u] = __builtin_nontemporal_load(
                    (const vf2*)(eap + (size_t)ev * D + k));
                hpv[u] = hpk[(size_t)(pk & 0xFFFFu) * 64 + lane];
                drv[u] = (jx < mm) ? __uint_as_float(pk & 0xFFFF0000u) : 0.0f;
            }
#pragma unroll
            for (int u = 0; u < 8; ++u) {
                float h0 = __uint_as_float(hpv[u][0] << 16);
                float h1 = __uint_as_float(hpv[u][0] & 0xFFFF0000u);
                float g0 = __uint_as_float(hpv[u][1] << 16);
                float g1 = __uint_as_float(hpv[u][1] & 0xFFFF0000u);
                amx = fmaf(drv[u], h0 + eav[u][0], amx);
                amy = fmaf(drv[u], h1 + eav[u][1], amy);
                asx = fmaf(drv[u], g0 + eav[u][0], asx);
                asy = fmaf(drv[u], g1 + eav[u][1], asy);
            }
        }
    }

    const size_t ob = (size_t)n * D + k;
    vf2 o0, o1;
    o0[0] = __uint_as_float(hpn[0] << 16)         + dc * amx;
    o0[1] = __uint_as_float(hpn[0] & 0xFFFF0000u) + dc * amy;
    o1[0] = __uint_as_float(hpn[1] << 16)         + dc * asx;
    o1[1] = __uint_as_float(hpn[1] & 0xFFFF0000u) + dc * asy;
    __builtin_nontemporal_store(o0, (vf2*)(om + ob));
    __builtin_nontemporal_store(o1, (vf2*)(os + ob));
}

extern "C" void kernel_launch(void* const* d_in, const int* in_sizes, int n_in,
                              void* d_out, int out_size, void* d_ws, size_t ws_size,
                              hipStream_t stream) {
    const float* x   = (const float*)d_in[0];
    const int*   ei  = (const int*)d_in[1];     // [2, E] int32
    const float* ea  = (const float*)d_in[2];   // [E, D]
    const float* Wm  = (const float*)d_in[3];
    const float* bm  = (const float*)d_in[4];
    const float* Ws  = (const float*)d_in[5];
    const float* bs  = (const float*)d_in[6];
    float* out = (float*)d_out;                 // [2, N, D]

    // workspace layout (16B-aligned chunks)
    char* w = (char*)d_ws;
    int*   count  = (int*)w;     w += (size_t)N_NODES * 4;
    int*   offset = (int*)w;     w += (size_t)N_NODES * 4;
    int*   cur    = (int*)w;     w += (size_t)N_NODES * 4;
    float* dis    = (float*)w;   w += (size_t)N_NODES * 4;
    int*   bsum   = (int*)w;     w += 4096;
    vu2*   meta   = (vu2*)w;     w += (size_t)N_EDGES * 8;         // 6.4 MB
    unsigned* hpk = (unsigned*)w;                                  // 25.6 MB
    float* om = out;
    float* os = out + (size_t)N_NODES * D;

    const int SCAN_BLKS = (N_NODES + 1023) / 1024;   // 49

    // 1. zero histogram (ws poisoned 0xAA once, never re-poisoned)
    hipMemsetAsync(count, 0, N_NODES * sizeof(int), stream);

    // 2. histogram of destinations
    hist_kernel<<<HIST_BLKS, 256, 0, stream>>>(ei, count);

    // 3-4. parallel exclusive scan (+ dis = rsqrt(deg) fused)
    scan1_kernel<<<SCAN_BLKS, 1024, 0, stream>>>(count, offset, dis, bsum);
    fixup_kernel<<<SCAN_BLKS, 1024, 0, stream>>>(bsum, offset, cur);

    // 5. scatter || gemm (scatter blocks first: latency long-pole overlaps gemm)
    fused_kernel<<<SCAT_BLKS + GEMM_BLKS, 256, 0, stream>>>(
        x, Wm, bm, Ws, bs, hpk, ei, dis, cur, meta);

    // 6. atomic-free CSR aggregation: one wave per node, batch-8 loads
    agg_kernel<<<N_NODES / 4, 256, 0, stream>>>(
        ea, (const vu2*)hpk, meta, offset, cur, dis, om, os);
}

// Round 11
// 262.384 us; speedup vs baseline: 2.6801x; 1.1337x over previous
//
#include <hip/hip_runtime.h>
#include <math.h>

#define N_NODES 50000
#define N_EDGES 800000
#define D 128

#define TILE_R 32
#define HIST_BLKS ((N_EDGES + 255) / 256)                 // 3125
#define SCAT_BLKS HIST_BLKS
#define GEMM_BLKS ((N_NODES + TILE_R - 1) / TILE_R)       // 1563

typedef float        vf2 __attribute__((ext_vector_type(2)));
typedef unsigned int vu2 __attribute__((ext_vector_type(2)));

// round-to-nearest-even fp32 -> bf16 bits (high 16)
static __device__ __forceinline__ unsigned f2bf(float f) {
    unsigned u = __float_as_uint(f);
    u += 0x7FFFu + ((u >> 16) & 1u);
    return u >> 16;
}

// ---------------------------------------------------------------------------
// count[col[e]]++  (int histogram of destination nodes)
// ---------------------------------------------------------------------------
__global__ __launch_bounds__(256) void hist_kernel(const int* __restrict__ ei,
                                                   int* __restrict__ count) {
    int e = blockIdx.x * blockDim.x + threadIdx.x;
    if (e < N_EDGES) {
        atomicAdd(&count[ei[N_EDGES + e]], 1);
    }
}

// ---------------------------------------------------------------------------
// scan1: per-block (1024) exclusive scan of count -> offset (local),
// block totals -> bsum, dis = rsqrt(count) fused.
// ---------------------------------------------------------------------------
__global__ __launch_bounds__(1024) void scan1_kernel(const int* __restrict__ count,
                                                     int* __restrict__ offset,
                                                     float* __restrict__ dis,
                                                     int* __restrict__ bsum) {
    __shared__ int wsum[16];
    const int tid = threadIdx.x;
    const int lane = tid & 63;
    const int wid = tid >> 6;
    const int i = blockIdx.x * 1024 + tid;

    int c = (i < N_NODES) ? count[i] : 0;
    int inc = c;
#pragma unroll
    for (int d = 1; d < 64; d <<= 1) {
        int v = __shfl_up(inc, d, 64);
        if (lane >= d) inc += v;
    }
    if (lane == 63) wsum[wid] = inc;
    __syncthreads();
    if (wid == 0) {
        int s = (lane < 16) ? wsum[lane] : 0;
#pragma unroll
        for (int d = 1; d < 16; d <<= 1) {
            int v = __shfl_up(s, d, 64);
            if (lane >= d) s += v;
        }
        if (lane < 16) wsum[lane] = s;
    }
    __syncthreads();
    int wpre = (wid > 0) ? wsum[wid - 1] : 0;
    if (i < N_NODES) {
        offset[i] = wpre + inc - c;
        dis[i] = (c > 0) ? rsqrtf((float)c) : 0.0f;
    }
    if (tid == 0) bsum[blockIdx.x] = wsum[15];
}

__global__ __launch_bounds__(1024) void fixup_kernel(const int* __restrict__ bsum,
                                                     int* __restrict__ offset,
                                                     int* __restrict__ cur) {
    __shared__ int pre_s;
    const int tid = threadIdx.x;
    const int blk = blockIdx.x;
    if ((tid >> 6) == 0) {
        int lane = tid & 63;
        int s = 0;
        for (int j = lane; j < blk; j += 64) s += bsum[j];
#pragma unroll
        for (int d = 32; d > 0; d >>= 1) s += __shfl_xor(s, d, 64);
        if (lane == 0) pre_s = s;
    }
    __syncthreads();
    int i = blk * 1024 + tid;
    if (i < N_NODES) {
        int o = offset[i] + pre_s;
        offset[i] = o;
        cur[i] = o;
    }
}

// ---------------------------------------------------------------------------
// FUSED: gemm (blocks [0, GEMM_BLKS)) || counting-sort scatter (rest).
// GEMM BLOCKS FIRST (r8/r10 A/B: gemm-first is 35 us faster — packing all
// atomic-contended scatter blocks at the dispatch front degrades their own
// contention throughput; compute-first fills CUs and scatter trickles in).
//
// gemm: h stored ONLY as packed bf16 hpk. Row r (512B): pair p=0..63:
//   word(p*2+0) = {bf16 hm[2p] | bf16 hm[2p+1]<<16}, word(p*2+1) = same for hs.
// scatter: meta[cur[col]++] = { e, row | bf16(dis[row])<<16 }  (8 B/edge)
// ---------------------------------------------------------------------------
__global__ __launch_bounds__(256) void fused_kernel(
    const float* __restrict__ x,
    const float* __restrict__ Wm, const float* __restrict__ bm,
    const float* __restrict__ Ws, const float* __restrict__ bs,
    unsigned* __restrict__ hpk,
    const int* __restrict__ ei, const float* __restrict__ dis,
    int* __restrict__ cur, vu2* __restrict__ meta)
{
    __shared__ float xs[TILE_R][D];
    const int tid = threadIdx.x;

    if (blockIdx.x >= GEMM_BLKS) {
        // ---------------- scatter part (thread-per-edge) ----------------
        int e = (blockIdx.x - GEMM_BLKS) * 256 + tid;
        if (e < N_EDGES) {
            int row = ei[e];
            int col = ei[N_EDGES + e];
            int p = atomicAdd(&cur[col], 1);
            vu2 v;
            v[0] = (unsigned)e;
            v[1] = (unsigned)row | (f2bf(dis[row]) << 16);
            meta[p] = v;
        }
        return;
    }

    // ---------------- gemm part ----------------
    const int r0 = blockIdx.x * TILE_R;

    for (int i = tid; i < TILE_R * D / 4; i += 256) {
        int rr = i / (D / 4);
        int cc = (i % (D / 4)) * 4;
        int r = r0 + rr;
        float4 v = make_float4(0.f, 0.f, 0.f, 0.f);
        if (r < N_NODES) v = *(const float4*)(x + (size_t)r * D + cc);
        *(float4*)(&xs[rr][cc]) = v;
    }
    __syncthreads();

    const int m = tid >> 7;              // 0 = mean, 1 = std
    const int p = (tid >> 1) & 63;       // column pair index
    const int rh = tid & 1;              // row half (16 rows each)
    const int c0 = p * 2;
    const float* __restrict__ W = m ? Ws : Wm;
    const float* __restrict__ b = m ? bs : bm;
    const float b0 = b[c0], b1 = b[c0 + 1];

    float acc0[16], acc1[16];
#pragma unroll
    for (int rr = 0; rr < 16; ++rr) { acc0[rr] = b0; acc1[rr] = b1; }

    const float* __restrict__ Wr0 = W + (size_t)c0 * D;
    const float* __restrict__ Wr1 = W + (size_t)(c0 + 1) * D;

    for (int kc = 0; kc < D; kc += 32) {
        float w0[32], w1[32];
#pragma unroll
        for (int j = 0; j < 32; j += 4) {
            float4 a = *(const float4*)(Wr0 + kc + j);
            float4 bb = *(const float4*)(Wr1 + kc + j);
            w0[j] = a.x; w0[j+1] = a.y; w0[j+2] = a.z; w0[j+3] = a.w;
            w1[j] = bb.x; w1[j+1] = bb.y; w1[j+2] = bb.z; w1[j+3] = bb.w;
        }
#pragma unroll
        for (int rr = 0; rr < 16; ++rr) {
            const float* xr = &xs[rh * 16 + rr][kc];
#pragma unroll
            for (int j = 0; j < 32; j += 4) {
                float4 xv = *(const float4*)(xr + j);   // LDS b128, 2-way bcast
                acc0[rr] = fmaf(xv.x, w0[j],     acc0[rr]);
                acc0[rr] = fmaf(xv.y, w0[j + 1], acc0[rr]);
                acc0[rr] = fmaf(xv.z, w0[j + 2], acc0[rr]);
                acc0[rr] = fmaf(xv.w, w0[j + 3], acc0[rr]);
                acc1[rr] = fmaf(xv.x, w1[j],     acc1[rr]);
                acc1[rr] = fmaf(xv.y, w1[j + 1], acc1[rr]);
                acc1[rr] = fmaf(xv.z, w1[j + 2], acc1[rr]);
                acc1[rr] = fmaf(xv.w, w1[j + 3], acc1[rr]);
            }
        }
    }

#pragma unroll
    for (int rr = 0; rr < 16; ++rr) {
        int r = r0 + rh * 16 + rr;
        if (r < N_NODES) {
            unsigned word = f2bf(acc0[rr]) | (f2bf(acc1[rr]) << 16);
            hpk[(size_t)r * 128 + p * 2 + m] = word;
        }
    }
}

// ---------------------------------------------------------------------------
// CSR aggregation: ONE WAVE per node, lane = column pair (8B).
// BATCH-8: per 8 edges, issue all 16 independent loads upfront into
// fully-unrolled register arrays (compile-time indices), then consume.
// No min-waves bound (a forced VGPR cap was the r6/r7 regression).
// Single-touch streams (meta, ea, out) nontemporal; hpk stays cached.
// Model: ~880 MB via vector path (ea 410 HBM-random + hpk 410 L3 + meta
// + out) at ~5 TB/s combined -> ~175 us; near the pattern's ceiling.
// ---------------------------------------------------------------------------
__global__ __launch_bounds__(256) void agg_kernel(
    const float* __restrict__ eap, const vu2* __restrict__ hpk,
    const vu2* __restrict__ meta,
    const int* __restrict__ offset, const int* __restrict__ cur,
    const float* __restrict__ dis,
    float* __restrict__ om, float* __restrict__ os)
{
    const int tid = threadIdx.x;
    const int lane = tid & 63;
    const int wid = tid >> 6;
    const int n = blockIdx.x * 4 + wid;

    const int start = offset[n];
    const int end = cur[n];          // after scatter, cur[n] == segment end
    const float dc = dis[n];
    const int k = lane * 2;

    // residual row from packed bf16 (issue early; cached buffer)
    vu2 hpn = hpk[(size_t)n * 64 + lane];

    float amx = 0.f, amy = 0.f, asx = 0.f, asy = 0.f;

    for (int jb = start; jb < end; jb += 64) {
        vu2 mt = (vu2)(0);
        if (jb + lane < end)
            mt = __builtin_nontemporal_load(meta + jb + lane);
        const int mm = min(64, end - jb);

        for (int j0 = 0; j0 < mm; j0 += 8) {
            vf2 eav[8]; vu2 hpv[8]; float drv[8];
#pragma unroll
            for (int u = 0; u < 8; ++u) {
                const int jx = j0 + u;
                const int jj = (jx < mm) ? jx : (mm - 1);   // clamp: valid addr
                unsigned ev = (unsigned)__builtin_amdgcn_readlane((int)mt[0], jj);
                unsigned pk = (unsigned)__builtin_amdgcn_readlane((int)mt[1], jj);
                eav[u] = __builtin_nontemporal_load(
                    (const vf2*)(eap + (size_t)ev * D + k));
                hpv[u] = hpk[(size_t)(pk & 0xFFFFu) * 64 + lane];
                drv[u] = (jx < mm) ? __uint_as_float(pk & 0xFFFF0000u) : 0.0f;
            }
#pragma unroll
            for (int u = 0; u < 8; ++u) {
                float h0 = __uint_as_float(hpv[u][0] << 16);
                float h1 = __uint_as_float(hpv[u][0] & 0xFFFF0000u);
                float g0 = __uint_as_float(hpv[u][1] << 16);
                float g1 = __uint_as_float(hpv[u][1] & 0xFFFF0000u);
                amx = fmaf(drv[u], h0 + eav[u][0], amx);
                amy = fmaf(drv[u], h1 + eav[u][1], amy);
                asx = fmaf(drv[u], g0 + eav[u][0], asx);
                asy = fmaf(drv[u], g1 + eav[u][1], asy);
            }
        }
    }

    const size_t ob = (size_t)n * D + k;
    vf2 o0, o1;
    o0[0] = __uint_as_float(hpn[0] << 16)         + dc * amx;
    o0[1] = __uint_as_float(hpn[0] & 0xFFFF0000u) + dc * amy;
    o1[0] = __uint_as_float(hpn[1] << 16)         + dc * asx;
    o1[1] = __uint_as_float(hpn[1] & 0xFFFF0000u) + dc * asy;
    __builtin_nontemporal_store(o0, (vf2*)(om + ob));
    __builtin_nontemporal_store(o1, (vf2*)(os + ob));
}

extern "C" void kernel_launch(void* const* d_in, const int* in_sizes, int n_in,
                              void* d_out, int out_size, void* d_ws, size_t ws_size,
                              hipStream_t stream) {
    const float* x   = (const float*)d_in[0];
    const int*   ei  = (const int*)d_in[1];     // [2, E] int32
    const float* ea  = (const float*)d_in[2];   // [E, D]
    const float* Wm  = (const float*)d_in[3];
    const float* bm  = (const float*)d_in[4];
    const float* Ws  = (const float*)d_in[5];
    const float* bs  = (const float*)d_in[6];
    float* out = (float*)d_out;                 // [2, N, D]

    // workspace layout (16B-aligned chunks)
    char* w = (char*)d_ws;
    int*   count  = (int*)w;     w += (size_t)N_NODES * 4;
    int*   offset = (int*)w;     w += (size_t)N_NODES * 4;
    int*   cur    = (int*)w;     w += (size_t)N_NODES * 4;
    float* dis    = (float*)w;   w += (size_t)N_NODES * 4;
    int*   bsum   = (int*)w;     w += 4096;
    vu2*   meta   = (vu2*)w;     w += (size_t)N_EDGES * 8;         // 6.4 MB
    unsigned* hpk = (unsigned*)w;                                  // 25.6 MB
    float* om = out;
    float* os = out + (size_t)N_NODES * D;

    const int SCAN_BLKS = (N_NODES + 1023) / 1024;   // 49

    // 1. zero histogram (ws poisoned 0xAA once, never re-poisoned)
    hipMemsetAsync(count, 0, N_NODES * sizeof(int), stream);

    // 2. histogram of destinations
    hist_kernel<<<HIST_BLKS, 256, 0, stream>>>(ei, count);

    // 3-4. parallel exclusive scan (+ dis = rsqrt(deg) fused)
    scan1_kernel<<<SCAN_BLKS, 1024, 0, stream>>>(count, offset, dis, bsum);
    fixup_kernel<<<SCAN_BLKS, 1024, 0, stream>>>(bsum, offset, cur);

    // 5. gemm || scatter (gemm blocks first — measured best ordering)
    fused_kernel<<<GEMM_BLKS + SCAT_BLKS, 256, 0, stream>>>(
        x, Wm, bm, Ws, bs, hpk, ei, dis, cur, meta);

    // 6. atomic-free CSR aggregation: one wave per node, batch-8 loads
    agg_kernel<<<N_NODES / 4, 256, 0, stream>>>(
        ea, (const vu2*)hpk, meta, offset, cur, dis, om, os);
}